// Round 1
// baseline (384.772 us; speedup 1.0000x reference)
//
#include <hip/hip_runtime.h>

typedef float  f32x16 __attribute__((ext_vector_type(16)));
typedef short  short8 __attribute__((ext_vector_type(8)));
typedef unsigned short u16;
typedef unsigned int   u32;

#define LOG2PI_F 1.8378770664093453f

__device__ __forceinline__ u16 f2bf(float f) {
  u32 u = __builtin_bit_cast(u32, f);
  u32 r = (u + 0x7FFFu + ((u >> 16) & 1u)) >> 16;
  return (u16)r;
}

// ---------------------------------------------------------------------------
// K0: emissions. E[t,j] = exp(log_em[t,j] - s_t), s_t = max_j log_em[t,j].
// Spart[block] = sum of s_t over the block's 64 t's.
// ---------------------------------------------------------------------------
__global__ __launch_bounds__(256) void emis_kernel(
    const float* __restrict__ Y, const float* __restrict__ mu,
    const float* __restrict__ rlv, int T,
    float* __restrict__ E, float* __restrict__ Spart)
{
  int j  = threadIdx.x & 31;
  int ts = threadIdx.x >> 5;  // 0..7

  float muv[16], iv[16];
  float slv = 0.f;
  const float4* mp = (const float4*)(mu  + (size_t)j * 16);
  const float4* rp = (const float4*)(rlv + (size_t)j * 16);
#pragma unroll
  for (int q = 0; q < 4; ++q) {
    float4 m4 = mp[q], r4 = rp[q];
    float mm[4] = {m4.x, m4.y, m4.z, m4.w};
    float rr[4] = {r4.x, r4.y, r4.z, r4.w};
#pragma unroll
    for (int e = 0; e < 4; ++e) {
      float lv = fminf(fmaxf(rr[e], -6.f), 6.f);
      muv[4*q+e] = mm[e];
      iv[4*q+e]  = __expf(-lv);
      slv += lv;
    }
  }
  float base_c = 16.f * LOG2PI_F + slv;

  float sacc = 0.f;
  for (int p2 = 0; p2 < 8; ++p2) {
    int t = blockIdx.x * 64 + p2 * 8 + ts;
    if (t < T) {
      float quad = 0.f;
      const float4* yp = (const float4*)(Y + (size_t)t * 16);
#pragma unroll
      for (int q = 0; q < 4; ++q) {
        float4 y4 = yp[q];
        float yy[4] = {y4.x, y4.y, y4.z, y4.w};
#pragma unroll
        for (int e = 0; e < 4; ++e) {
          float d = yy[e] - muv[4*q+e];
          quad = fmaf(d * d, iv[4*q+e], quad);
        }
      }
      float lem = -0.5f * (base_c + quad);
      float mx = lem;
#pragma unroll
      for (int m = 16; m >= 1; m >>= 1) mx = fmaxf(mx, __shfl_xor(mx, m, 32));
      E[(size_t)t * 32 + j] = __expf(lem - mx);
      if (j == 0) sacc += mx;
    }
  }
  __shared__ float sred[8];
  if (j == 0) sred[ts] = sacc;
  __syncthreads();
  if (threadIdx.x == 0) {
    float s = 0.f;
#pragma unroll
    for (int k = 0; k < 8; ++k) s += sred[k];
    Spart[blockIdx.x] = s;
  }
}

// ---------------------------------------------------------------------------
// K1: B_t[i,j] = softmax_j(b[i,j] + W[i,j,:]·x_t) * E[t,j], stored bf16 in
// A-fragment order for mfma_f32_32x32x16_bf16 with A = B_t^T:
//   flat(i,j) = (j + 32*((i>>3)&1))*16 + (i>>4)*8 + (i&7)
// B_0 is overridden to the identity so all chain blocks run 64 uniform steps.
// One workgroup = 1024 threads = thread per (i,j), handles 32 consecutive t.
// ---------------------------------------------------------------------------
__global__ __launch_bounds__(1024) void bmat_kernel(
    const float* __restrict__ X, const float* __restrict__ E,
    const float* __restrict__ W, const float* __restrict__ b,
    int T, int seg_t0, u16* __restrict__ Bseg)
{
  int tid = threadIdx.x;
  int i = tid >> 5, j = tid & 31;

  float w[16];
  const float4* wp = (const float4*)(W + (size_t)(i * 32 + j) * 16);
#pragma unroll
  for (int q = 0; q < 4; ++q) {
    float4 v = wp[q];
    w[4*q+0] = v.x; w[4*q+1] = v.y; w[4*q+2] = v.z; w[4*q+3] = v.w;
  }
  float bv = b[i * 32 + j];

  __shared__ __align__(16) float xs[32 * 16];
  __shared__ float es[32 * 32];

  int t0 = seg_t0 + blockIdx.x * 32;  // global t of first in chunk
  if (tid < 512) {
    int tt = t0 + (tid >> 4);
    xs[tid] = (tt < T) ? X[(size_t)t0 * 16 + tid] : 0.f;
  }
  {
    int tt = t0 + (tid >> 5);
    es[tid] = (tt < T) ? E[(size_t)t0 * 32 + tid] : 0.f;
  }
  __syncthreads();

  int flat = (j + 32 * ((i >> 3) & 1)) * 16 + ((i >> 4) << 3) + (i & 7);
  u16* outp = Bseg + (size_t)(blockIdx.x * 32) * 1024 + flat;

  for (int tl = 0; tl < 32; ++tl) {
    int t = t0 + tl;
    if (t >= T) break;
    float lg = bv;
    const float4* xp = (const float4*)(xs + tl * 16);
#pragma unroll
    for (int q = 0; q < 4; ++q) {
      float4 x4 = xp[q];
      lg = fmaf(w[4*q+0], x4.x, lg);
      lg = fmaf(w[4*q+1], x4.y, lg);
      lg = fmaf(w[4*q+2], x4.z, lg);
      lg = fmaf(w[4*q+3], x4.w, lg);
    }
    // |logits| <= ||Wrow||*||x|| + |b| ~ 3 : exp without max-subtract is safe
    float pz = __expf(lg);
    float sz = pz;
#pragma unroll
    for (int m = 16; m >= 1; m >>= 1) sz += __shfl_xor(sz, m, 32);
    float Bv = (pz / sz) * es[tl * 32 + j];
    if (t == 0) Bv = (i == j) ? 1.f : 0.f;  // B_0 := I
    *outp = f2bf(Bv);
    outp += 1024;
  }
}

// ---------------------------------------------------------------------------
// Chain kernel: per block, S ← (in_mat)^T-chain via 2x mfma_f32_32x32x16_bf16.
// State S held in C/D layout (verified: col = lane&31, row=(r&3)+8*(r>>2)+4*h).
// C/D → B-operand conversion: 8x v_cvt_pk_bf16_f32 + 4x v_permlane32_swap_b32.
// Power-of-2 renorm every 8 steps; exponent accumulated in Eacc.
// ---------------------------------------------------------------------------
__device__ __forceinline__ void acc_to_bops(const f32x16& acc, uint4& B1, uint4& B2) {
  u32 pk[8];
#pragma unroll
  for (int q = 0; q < 8; ++q) {
    u32 r;
    asm("v_cvt_pk_bf16_f32 %0, %1, %2" : "=v"(r) : "v"(acc[2*q]), "v"(acc[2*q+1]));
    pk[q] = r;
  }
  // pk0={r0,1|r4,5} pk1={r2,3|r6,7} pk2={r8,9|r12,13} pk3={r10,11|r14,15}
  asm("v_permlane32_swap_b32 %0, %1" : "+v"(pk[0]), "+v"(pk[2]));
  asm("v_permlane32_swap_b32 %0, %1" : "+v"(pk[1]), "+v"(pk[3]));
  B1 = make_uint4(pk[0], pk[1], pk[2], pk[3]);
  asm("v_permlane32_swap_b32 %0, %1" : "+v"(pk[4]), "+v"(pk[6]));
  asm("v_permlane32_swap_b32 %0, %1" : "+v"(pk[5]), "+v"(pk[7]));
  B2 = make_uint4(pk[4], pk[5], pk[6], pk[7]);
}

__device__ __forceinline__ void renorm(f32x16& acc, float& Eacc) {
  float m = acc[0];
#pragma unroll
  for (int r = 1; r < 16; ++r) m = fmaxf(m, acc[r]);
#pragma unroll
  for (int off = 32; off >= 1; off >>= 1) m = fmaxf(m, __shfl_xor(m, off, 64));
  if (m > 0.f) {
    int ex;
    frexpf(m, &ex);
    float sc = ldexpf(1.f, -ex);
#pragma unroll
    for (int r = 0; r < 16; ++r) acc[r] *= sc;
    Eacc += (float)ex;
  }
}

__global__ __launch_bounds__(64) void chain_kernel(
    const uint4* __restrict__ in_frags, const float* __restrict__ in_E,
    int mpb, u16* __restrict__ out_frags, float* __restrict__ out_E,
    float* __restrict__ out_final)
{
  int l = threadIdx.x;
  long base = (long)blockIdx.x * mpb;
  const uint4* p = in_frags + base * 128 + l * 2;

  uint4 bufA[8], bufB[8];
#pragma unroll
  for (int u = 0; u < 8; ++u) { bufA[u] = p[u * 128]; bufB[u] = p[u * 128 + 1]; }

  int col = l & 31, h = l >> 5;
  f32x16 acc, zero16;
#pragma unroll
  for (int r = 0; r < 16; ++r) {
    int row = (r & 3) + 8 * (r >> 2) + 4 * h;
    acc[r]  = (row == col) ? 1.f : 0.f;
    zero16[r] = 0.f;
  }

  float Eacc = 0.f;
  if (in_E) {
    for (int k = 0; k < mpb; ++k) Eacc += in_E[base + k];
  }

  for (int s = 0; s < mpb; s += 8) {
#pragma unroll
    for (int u = 0; u < 8; ++u) {
      uint4 B1, B2;
      acc_to_bops(acc, B1, B2);
      short8 A1 = __builtin_bit_cast(short8, bufA[u]);
      short8 A2 = __builtin_bit_cast(short8, bufB[u]);
      int nm = s + u + 8;
      if (nm < mpb) { bufA[u] = p[nm * 128]; bufB[u] = p[nm * 128 + 1]; }
      f32x16 t1 = __builtin_amdgcn_mfma_f32_32x32x16_bf16(
          A1, __builtin_bit_cast(short8, B1), zero16, 0, 0, 0);
      acc = __builtin_amdgcn_mfma_f32_32x32x16_bf16(
          A2, __builtin_bit_cast(short8, B2), t1, 0, 0, 0);
    }
    renorm(acc, Eacc);
  }

  if (out_final) {
#pragma unroll
    for (int r = 0; r < 16; ++r) {
      int row = (r & 3) + 8 * (r >> 2) + 4 * h;
      out_final[row * 32 + col] = acc[r];
    }
    if (l == 0) *out_E = Eacc;
  } else {
#pragma unroll
    for (int r = 0; r < 16; ++r) {
      int row = (r & 3) + 8 * (r >> 2) + 4 * h;
      int flat = (row + 32 * ((col >> 3) & 1)) * 16 + ((col >> 4) << 3) + (col & 7);
      out_frags[(size_t)blockIdx.x * 1024 + flat] = f2bf(acc[r]);
    }
    if (l == 0) out_E[blockIdx.x] = Eacc;
  }
}

// ---------------------------------------------------------------------------
// K3b: a0 = softmax(init)*E[0,:]; a_f[j] = sum_m a0[m]*Mtot[m,j] (MT = Mtot^T
// row-major); out = log(sum a_f) + sum s_t + ln2 * Egrand.
// ---------------------------------------------------------------------------
__global__ __launch_bounds__(64) void finalize_kernel(
    const float* __restrict__ init_logits, const float* __restrict__ E,
    const float* __restrict__ Spart, int nSpart,
    const float* __restrict__ MT, const float* __restrict__ Egrand,
    float* __restrict__ out)
{
  int l = threadIdx.x;
  int j = l & 31;

  float il = init_logits[j];
  float mx = il;
#pragma unroll
  for (int m = 16; m >= 1; m >>= 1) mx = fmaxf(mx, __shfl_xor(mx, m, 32));
  float pz = __expf(il - mx);
  float sz = pz;
#pragma unroll
  for (int m = 16; m >= 1; m >>= 1) sz += __shfl_xor(sz, m, 32);
  float a0 = (pz / sz) * E[j];

  float rbuf[32];
  const float4* rowp = (const float4*)(MT + j * 32);
#pragma unroll
  for (int q = 0; q < 8; ++q) {
    float4 v = rowp[q];
    rbuf[4*q+0] = v.x; rbuf[4*q+1] = v.y; rbuf[4*q+2] = v.z; rbuf[4*q+3] = v.w;
  }
  float af = 0.f;
#pragma unroll
  for (int m = 0; m < 32; ++m) af = fmaf(__shfl(a0, m, 32), rbuf[m], af);

  float sa = af;
#pragma unroll
  for (int m = 16; m >= 1; m >>= 1) sa += __shfl_xor(sa, m, 32);

  double ss = 0.0;
  for (int idx = l; idx < nSpart; idx += 64) ss += (double)Spart[idx];
#pragma unroll
  for (int m = 32; m >= 1; m >>= 1) ss += __shfl_xor(ss, m, 64);

  if (l == 0) {
    double r = log((double)sa) + ss + 0.6931471805599453 * (double)(*Egrand);
    out[0] = (float)r;
  }
}

// ---------------------------------------------------------------------------
extern "C" void kernel_launch(void* const* d_in, const int* in_sizes, int n_in,
                              void* d_out, int out_size, void* d_ws, size_t ws_size,
                              hipStream_t stream) {
  const float* X   = (const float*)d_in[0];
  const float* Y   = (const float*)d_in[1];
  const float* il  = (const float*)d_in[2];
  const float* W   = (const float*)d_in[3];
  const float* b   = (const float*)d_in[4];
  const float* mu  = (const float*)d_in[5];
  const float* rlv = (const float*)d_in[6];
  float* out = (float*)d_out;

  int T   = in_sizes[0] / 16;
  int NB0 = (T + 63) / 64;
  int NB2 = T / 64;  // T = 131072: multiple of 64

  char* ws = (char*)d_ws;
  size_t off = 0;
  auto alloc = [&](size_t bytes) -> void* {
    void* p = ws + off;
    off = (off + bytes + 255) & ~(size_t)255;
    return p;
  };
  float* E      = (float*)alloc((size_t)T * 32 * 4);
  float* Spart  = (float*)alloc((size_t)NB0 * 4);
  u16*   Sg     = (u16*)  alloc((size_t)NB2 * 2048);
  float* Eg     = (float*)alloc((size_t)NB2 * 4);
  u16*   Rf     = (u16*)  alloc((size_t)64 * 2048);
  float* ER     = (float*)alloc((size_t)64 * 4);
  float* MT     = (float*)alloc(4096);
  float* Egrand = (float*)alloc(256);

  size_t avail = (ws_size > off) ? (ws_size - off) : 0;
  long tseg = (long)(avail / 2048) & ~63L;
  if (tseg < 64) tseg = 64;
  if (tseg > T) tseg = T;
  int TSEG = (int)tseg;
  u16* Bseg = (u16*)(ws + off);

  emis_kernel<<<NB0, 256, 0, stream>>>(Y, mu, rlv, T, E, Spart);

  for (int t0 = 0; t0 < T; t0 += TSEG) {
    int tn = (T - t0 < TSEG) ? (T - t0) : TSEG;
    bmat_kernel<<<(tn + 31) / 32, 1024, 0, stream>>>(X, E, W, b, T, t0, Bseg);
    int bps = tn / 64;
    chain_kernel<<<bps, 64, 0, stream>>>(
        (const uint4*)Bseg, nullptr, 64,
        Sg + (size_t)(t0 / 64) * 1024, Eg + t0 / 64, nullptr);
  }

  int mpb1 = NB2 / 64;  // 32
  chain_kernel<<<64, 64, 0, stream>>>((const uint4*)Sg, Eg, mpb1, Rf, ER, nullptr);
  chain_kernel<<<1, 64, 0, stream>>>((const uint4*)Rf, ER, 64, nullptr, Egrand, MT);

  finalize_kernel<<<1, 64, 0, stream>>>(il, E, Spart, NB0, MT, Egrand, out);
}

// Round 2
// 251.017 us; speedup vs baseline: 1.5329x; 1.5329x over previous
//
#include <hip/hip_runtime.h>

typedef float  f32x16 __attribute__((ext_vector_type(16)));
typedef short  short8 __attribute__((ext_vector_type(8)));
typedef unsigned short u16;
typedef unsigned int   u32;

#define LOG2PI_F 1.8378770664093453f

__device__ __forceinline__ u16 f2bf(float f) {
  u32 u = __builtin_bit_cast(u32, f);
  u32 r = (u + 0x7FFFu + ((u >> 16) & 1u)) >> 16;
  return (u16)r;
}

// ---------------------------------------------------------------------------
// K0: emissions. E[t,j] = exp(log_em[t,j] - s_t), s_t = max_j log_em[t,j].
// Spart[block] = sum of s_t over the block's 64 t's.
// ---------------------------------------------------------------------------
__global__ __launch_bounds__(256) void emis_kernel(
    const float* __restrict__ Y, const float* __restrict__ mu,
    const float* __restrict__ rlv, int T,
    float* __restrict__ E, float* __restrict__ Spart)
{
  int j  = threadIdx.x & 31;
  int ts = threadIdx.x >> 5;  // 0..7

  float muv[16], iv[16];
  float slv = 0.f;
  const float4* mp = (const float4*)(mu  + (size_t)j * 16);
  const float4* rp = (const float4*)(rlv + (size_t)j * 16);
#pragma unroll
  for (int q = 0; q < 4; ++q) {
    float4 m4 = mp[q], r4 = rp[q];
    float mm[4] = {m4.x, m4.y, m4.z, m4.w};
    float rr[4] = {r4.x, r4.y, r4.z, r4.w};
#pragma unroll
    for (int e = 0; e < 4; ++e) {
      float lv = fminf(fmaxf(rr[e], -6.f), 6.f);
      muv[4*q+e] = mm[e];
      iv[4*q+e]  = __expf(-lv);
      slv += lv;
    }
  }
  float base_c = 16.f * LOG2PI_F + slv;

  float sacc = 0.f;
  for (int p2 = 0; p2 < 8; ++p2) {
    int t = blockIdx.x * 64 + p2 * 8 + ts;
    if (t < T) {
      float quad = 0.f;
      const float4* yp = (const float4*)(Y + (size_t)t * 16);
#pragma unroll
      for (int q = 0; q < 4; ++q) {
        float4 y4 = yp[q];
        float yy[4] = {y4.x, y4.y, y4.z, y4.w};
#pragma unroll
        for (int e = 0; e < 4; ++e) {
          float d = yy[e] - muv[4*q+e];
          quad = fmaf(d * d, iv[4*q+e], quad);
        }
      }
      float lem = -0.5f * (base_c + quad);
      float mx = lem;
#pragma unroll
      for (int m = 16; m >= 1; m >>= 1) mx = fmaxf(mx, __shfl_xor(mx, m, 32));
      E[(size_t)t * 32 + j] = __expf(lem - mx);
      if (j == 0) sacc += mx;
    }
  }
  __shared__ float sred[8];
  if (j == 0) sred[ts] = sacc;
  __syncthreads();
  if (threadIdx.x == 0) {
    float s = 0.f;
#pragma unroll
    for (int k = 0; k < 8; ++k) s += sred[k];
    Spart[blockIdx.x] = s;
  }
}

// ---------------------------------------------------------------------------
// Prep: Wfrag[i][lane][e] = bf16(W[i][j=lane&31][d=(lane>>5)*8+e] / ln2)
// (A-operand fragments for mfma_f32_32x32x16_bf16), bprime = b / ln2.
// ---------------------------------------------------------------------------
__global__ __launch_bounds__(256) void prep_kernel(
    const float* __restrict__ W, const float* __restrict__ b,
    u16* __restrict__ Wfrag, float* __restrict__ bprime)
{
  const float INVLN2 = 1.4426950408889634f;
  int idx = blockIdx.x * 256 + threadIdx.x;
  if (idx < 16384) {
    int i = idx >> 9, rem = idx & 511, l = rem >> 3, e = rem & 7;
    int j = l & 31, h = l >> 5;
    Wfrag[idx] = f2bf(W[i * 512 + j * 16 + h * 8 + e] * INVLN2);
  }
  if (idx < 1024) bprime[idx] = b[idx] * INVLN2;
}

// ---------------------------------------------------------------------------
// bmat2: B_t[i,j] = softmax_j(b + W·x_t) * E[t,j] via MFMA.
// Per 32-t group, per wave w: 8 MFMAs (i = 8w..8w+7), tile = [rows j][cols t].
// Softmax over j = in-register 15-add tree + 1 permlane32_swap.
// Chunk {B[8w+e][j][t]}e=0..7 lives in one lane -> cvt_pk x4 -> dwordx4 store
// straight into the chain's fragment layout. No LDS, no shuffles.
// ---------------------------------------------------------------------------
__device__ __forceinline__ void bmat2_batch(
    const short8* wf, int ib0, short8 xf, const float* __restrict__ bprime,
    int h, const float* ee, u32* cw /* [32] */)
{
  f32x16 a[4];
#pragma unroll
  for (int e = 0; e < 4; ++e) {
    f32x16 c;
#pragma unroll
    for (int qd = 0; qd < 4; ++qd) {
      float4 b4 = *(const float4*)(bprime + (ib0 + e) * 32 + 4 * h + 8 * qd);
      c[4*qd+0] = b4.x; c[4*qd+1] = b4.y; c[4*qd+2] = b4.z; c[4*qd+3] = b4.w;
    }
    a[e] = __builtin_amdgcn_mfma_f32_32x32x16_bf16(wf[e], xf, c, 0, 0, 0);
  }
#pragma unroll
  for (int e = 0; e < 4; ++e) {
    float s = 0.f;
#pragma unroll
    for (int r = 0; r < 16; ++r) { float p = exp2f(a[e][r]); a[e][r] = p; s += p; }
    float s2 = s, s3 = s;
    asm("v_permlane32_swap_b32 %0, %1" : "+v"(s2), "+v"(s3));
    float rv = __builtin_amdgcn_rcpf(s2 + s3);
#pragma unroll
    for (int r = 0; r < 16; ++r) a[e][r] *= rv;
  }
#pragma unroll
  for (int r = 0; r < 16; ++r) {
    float e0 = a[0][r] * ee[r], e1 = a[1][r] * ee[r];
    float e2 = a[2][r] * ee[r], e3 = a[3][r] * ee[r];
    u32 w0, w1;
    asm("v_cvt_pk_bf16_f32 %0, %1, %2" : "=v"(w0) : "v"(e0), "v"(e1));
    asm("v_cvt_pk_bf16_f32 %0, %1, %2" : "=v"(w1) : "v"(e2), "v"(e3));
    cw[r*2+0] = w0; cw[r*2+1] = w1;
  }
}

__global__ __launch_bounds__(256, 2) void bmat2_kernel(
    const float* __restrict__ X, const float* __restrict__ E,
    const u16* __restrict__ Wfrag, const float* __restrict__ bprime,
    int T, int seg_t0, int tn, u16* __restrict__ Bseg)
{
  int tid = threadIdx.x;
  int w = tid >> 6, l = tid & 63, tc = l & 31, h = l >> 5;

  short8 wf[8];
#pragma unroll
  for (int it = 0; it < 8; ++it)
    wf[it] = *(const short8*)(Wfrag + ((size_t)(8*w + it) * 64 + l) * 8);

  for (int gi = 0; gi < 4; ++gi) {
    int trel0 = blockIdx.x * 128 + gi * 32;
    if (trel0 >= tn) return;
    int trel = trel0 + tc;
    int tglob = seg_t0 + trel;

    // X B-operand fragment: lane holds X[t = tglob][d = 8h+e]
    float4 xa = *(const float4*)(X + (size_t)tglob * 16 + 8 * h);
    float4 xb = *(const float4*)(X + (size_t)tglob * 16 + 8 * h + 4);
    u32 xp0, xp1, xp2, xp3;
    asm("v_cvt_pk_bf16_f32 %0, %1, %2" : "=v"(xp0) : "v"(xa.x), "v"(xa.y));
    asm("v_cvt_pk_bf16_f32 %0, %1, %2" : "=v"(xp1) : "v"(xa.z), "v"(xa.w));
    asm("v_cvt_pk_bf16_f32 %0, %1, %2" : "=v"(xp2) : "v"(xb.x), "v"(xb.y));
    asm("v_cvt_pk_bf16_f32 %0, %1, %2" : "=v"(xp3) : "v"(xb.z), "v"(xb.w));
    uint4 xu = make_uint4(xp0, xp1, xp2, xp3);
    short8 xf = __builtin_bit_cast(short8, xu);

    // E[t][j] quads for this lane's j-set (j = 4h + 8qd + p)
    float ee[16];
#pragma unroll
    for (int qd = 0; qd < 4; ++qd) {
      float4 eq = *(const float4*)(E + (size_t)tglob * 32 + 4 * h + 8 * qd);
      ee[4*qd+0] = eq.x; ee[4*qd+1] = eq.y; ee[4*qd+2] = eq.z; ee[4*qd+3] = eq.w;
    }

    u32 cA[32], cB[32];
    bmat2_batch(wf,     8*w,     xf, bprime, h, ee, cA);
    bmat2_batch(wf + 4, 8*w + 4, xf, bprime, h, ee, cB);

#pragma unroll
    for (int qd = 0; qd < 4; ++qd) {
#pragma unroll
      for (int p = 0; p < 4; ++p) {
        int r = 4*qd + p;
        int j = 4*h + 8*qd + p;
        uint4 v = make_uint4(cA[2*r], cA[2*r+1], cB[2*r], cB[2*r+1]);
        if (tglob == 0) {
          // B_0 := I
          u32 i0 = 8*w;
          u32 w0 = ((i0+0 == (u32)j) ? 0x3F80u : 0u) | (((i0+1 == (u32)j) ? 0x3F80u : 0u) << 16);
          u32 w1 = ((i0+2 == (u32)j) ? 0x3F80u : 0u) | (((i0+3 == (u32)j) ? 0x3F80u : 0u) << 16);
          u32 w2 = ((i0+4 == (u32)j) ? 0x3F80u : 0u) | (((i0+5 == (u32)j) ? 0x3F80u : 0u) << 16);
          u32 w3 = ((i0+6 == (u32)j) ? 0x3F80u : 0u) | (((i0+7 == (u32)j) ? 0x3F80u : 0u) << 16);
          v = make_uint4(w0, w1, w2, w3);
        }
        *(uint4*)(Bseg + (size_t)trel * 1024 + (size_t)((j + 32*(w & 1)) * 16 + 8*(w >> 1))) = v;
      }
    }
  }
}

// ---------------------------------------------------------------------------
// Chain kernel: per block, S ← (in_mat)^T-chain via 2x mfma_f32_32x32x16_bf16.
// State S held in C/D layout (col = lane&31, row=(r&3)+8*(r>>2)+4*h).
// C/D → B-operand conversion: 8x v_cvt_pk_bf16_f32 + 4x v_permlane32_swap_b32.
// Power-of-2 renorm every 8 steps; exponent accumulated in Eacc.
// ---------------------------------------------------------------------------
__device__ __forceinline__ void acc_to_bops(const f32x16& acc, uint4& B1, uint4& B2) {
  u32 pk[8];
#pragma unroll
  for (int q = 0; q < 8; ++q) {
    u32 r;
    asm("v_cvt_pk_bf16_f32 %0, %1, %2" : "=v"(r) : "v"(acc[2*q]), "v"(acc[2*q+1]));
    pk[q] = r;
  }
  asm("v_permlane32_swap_b32 %0, %1" : "+v"(pk[0]), "+v"(pk[2]));
  asm("v_permlane32_swap_b32 %0, %1" : "+v"(pk[1]), "+v"(pk[3]));
  B1 = make_uint4(pk[0], pk[1], pk[2], pk[3]);
  asm("v_permlane32_swap_b32 %0, %1" : "+v"(pk[4]), "+v"(pk[6]));
  asm("v_permlane32_swap_b32 %0, %1" : "+v"(pk[5]), "+v"(pk[7]));
  B2 = make_uint4(pk[4], pk[5], pk[6], pk[7]);
}

__device__ __forceinline__ void renorm(f32x16& acc, float& Eacc) {
  float m = acc[0];
#pragma unroll
  for (int r = 1; r < 16; ++r) m = fmaxf(m, acc[r]);
#pragma unroll
  for (int off = 32; off >= 1; off >>= 1) m = fmaxf(m, __shfl_xor(m, off, 64));
  if (m > 0.f) {
    int ex;
    frexpf(m, &ex);
    float sc = ldexpf(1.f, -ex);
#pragma unroll
    for (int r = 0; r < 16; ++r) acc[r] *= sc;
    Eacc += (float)ex;
  }
}

__global__ __launch_bounds__(64) void chain_kernel(
    const uint4* __restrict__ in_frags, const float* __restrict__ in_E,
    int mpb, u16* __restrict__ out_frags, float* __restrict__ out_E,
    float* __restrict__ out_final)
{
  int l = threadIdx.x;
  long base = (long)blockIdx.x * mpb;
  const uint4* p = in_frags + base * 128 + l * 2;

  uint4 bufA[8], bufB[8];
#pragma unroll
  for (int u = 0; u < 8; ++u) { bufA[u] = p[u * 128]; bufB[u] = p[u * 128 + 1]; }

  int col = l & 31, h = l >> 5;
  f32x16 acc, zero16;
#pragma unroll
  for (int r = 0; r < 16; ++r) {
    int row = (r & 3) + 8 * (r >> 2) + 4 * h;
    acc[r]  = (row == col) ? 1.f : 0.f;
    zero16[r] = 0.f;
  }

  float Eacc = 0.f;
  if (in_E) {
    for (int k = 0; k < mpb; ++k) Eacc += in_E[base + k];
  }

  for (int s = 0; s < mpb; s += 8) {
#pragma unroll
    for (int u = 0; u < 8; ++u) {
      uint4 B1, B2;
      acc_to_bops(acc, B1, B2);
      short8 A1 = __builtin_bit_cast(short8, bufA[u]);
      short8 A2 = __builtin_bit_cast(short8, bufB[u]);
      int nm = s + u + 8;
      if (nm < mpb) { bufA[u] = p[nm * 128]; bufB[u] = p[nm * 128 + 1]; }
      f32x16 t1 = __builtin_amdgcn_mfma_f32_32x32x16_bf16(
          A1, __builtin_bit_cast(short8, B1), zero16, 0, 0, 0);
      acc = __builtin_amdgcn_mfma_f32_32x32x16_bf16(
          A2, __builtin_bit_cast(short8, B2), t1, 0, 0, 0);
    }
    renorm(acc, Eacc);
  }

  if (out_final) {
#pragma unroll
    for (int r = 0; r < 16; ++r) {
      int row = (r & 3) + 8 * (r >> 2) + 4 * h;
      out_final[row * 32 + col] = acc[r];
    }
    if (l == 0) *out_E = Eacc;
  } else {
#pragma unroll
    for (int r = 0; r < 16; ++r) {
      int row = (r & 3) + 8 * (r >> 2) + 4 * h;
      int flat = (row + 32 * ((col >> 3) & 1)) * 16 + ((col >> 4) << 3) + (col & 7);
      out_frags[(size_t)blockIdx.x * 1024 + flat] = f2bf(acc[r]);
    }
    if (l == 0) out_E[blockIdx.x] = Eacc;
  }
}

// ---------------------------------------------------------------------------
// finalize: a0 = softmax(init)*E[0,:]; a_f[j] = sum_m a0[m]*Mtot[m,j];
// out = log(sum a_f) + sum s_t + ln2 * Egrand.
// ---------------------------------------------------------------------------
__global__ __launch_bounds__(64) void finalize_kernel(
    const float* __restrict__ init_logits, const float* __restrict__ E,
    const float* __restrict__ Spart, int nSpart,
    const float* __restrict__ MT, const float* __restrict__ Egrand,
    float* __restrict__ out)
{
  int l = threadIdx.x;
  int j = l & 31;

  float il = init_logits[j];
  float mx = il;
#pragma unroll
  for (int m = 16; m >= 1; m >>= 1) mx = fmaxf(mx, __shfl_xor(mx, m, 32));
  float pz = __expf(il - mx);
  float sz = pz;
#pragma unroll
  for (int m = 16; m >= 1; m >>= 1) sz += __shfl_xor(sz, m, 32);
  float a0 = (pz / sz) * E[j];

  float rbuf[32];
  const float4* rowp = (const float4*)(MT + j * 32);
#pragma unroll
  for (int q = 0; q < 8; ++q) {
    float4 v = rowp[q];
    rbuf[4*q+0] = v.x; rbuf[4*q+1] = v.y; rbuf[4*q+2] = v.z; rbuf[4*q+3] = v.w;
  }
  float af = 0.f;
#pragma unroll
  for (int m = 0; m < 32; ++m) af = fmaf(__shfl(a0, m, 32), rbuf[m], af);

  float sa = af;
#pragma unroll
  for (int m = 16; m >= 1; m >>= 1) sa += __shfl_xor(sa, m, 32);

  double ss = 0.0;
  for (int idx = l; idx < nSpart; idx += 64) ss += (double)Spart[idx];
#pragma unroll
  for (int m = 32; m >= 1; m >>= 1) ss += __shfl_xor(ss, m, 64);

  if (l == 0) {
    double r = log((double)sa) + ss + 0.6931471805599453 * (double)(*Egrand);
    out[0] = (float)r;
  }
}

// ---------------------------------------------------------------------------
extern "C" void kernel_launch(void* const* d_in, const int* in_sizes, int n_in,
                              void* d_out, int out_size, void* d_ws, size_t ws_size,
                              hipStream_t stream) {
  const float* X   = (const float*)d_in[0];
  const float* Y   = (const float*)d_in[1];
  const float* il  = (const float*)d_in[2];
  const float* W   = (const float*)d_in[3];
  const float* b   = (const float*)d_in[4];
  const float* mu  = (const float*)d_in[5];
  const float* rlv = (const float*)d_in[6];
  float* out = (float*)d_out;

  int T   = in_sizes[0] / 16;
  int NB0 = (T + 63) / 64;
  int NB2 = T / 64;  // T = 131072: multiple of 64

  char* ws = (char*)d_ws;
  size_t off = 0;
  auto alloc = [&](size_t bytes) -> void* {
    void* p = ws + off;
    off = (off + bytes + 255) & ~(size_t)255;
    return p;
  };
  float* E      = (float*)alloc((size_t)T * 32 * 4);
  float* Spart  = (float*)alloc((size_t)NB0 * 4);
  u16*   Sg     = (u16*)  alloc((size_t)NB2 * 2048);
  float* Eg     = (float*)alloc((size_t)NB2 * 4);
  u16*   Rf     = (u16*)  alloc((size_t)64 * 2048);
  float* ER     = (float*)alloc((size_t)64 * 4);
  float* MT     = (float*)alloc(4096);
  float* Egrand = (float*)alloc(256);
  u16*   Wfrag  = (u16*)  alloc((size_t)16384 * 2);
  float* bprime = (float*)alloc((size_t)1024 * 4);

  size_t avail = (ws_size > off) ? (ws_size - off) : 0;
  long tseg = (long)(avail / 2048) & ~63L;
  if (tseg < 64) tseg = 64;
  if (tseg > T) tseg = T;
  int TSEG = (int)tseg;
  u16* Bseg = (u16*)(ws + off);

  prep_kernel<<<64, 256, 0, stream>>>(W, b, Wfrag, bprime);
  emis_kernel<<<NB0, 256, 0, stream>>>(Y, mu, rlv, T, E, Spart);

  for (int t0 = 0; t0 < T; t0 += TSEG) {
    int tn = (T - t0 < TSEG) ? (T - t0) : TSEG;
    int nblk = (tn + 127) / 128;
    bmat2_kernel<<<nblk, 256, 0, stream>>>(X, E, Wfrag, bprime, T, t0, tn, Bseg);
    int bps = tn / 64;
    chain_kernel<<<bps, 64, 0, stream>>>(
        (const uint4*)Bseg, nullptr, 64,
        Sg + (size_t)(t0 / 64) * 1024, Eg + t0 / 64, nullptr);
  }

  int mpb1 = NB2 / 64;  // 32
  chain_kernel<<<64, 64, 0, stream>>>((const uint4*)Sg, Eg, mpb1, Rf, ER, nullptr);
  chain_kernel<<<1, 64, 0, stream>>>((const uint4*)Rf, ER, 64, nullptr, Egrand, MT);

  finalize_kernel<<<1, 64, 0, stream>>>(il, E, Spart, NB0, MT, Egrand, out);
}

// Round 5
// 247.191 us; speedup vs baseline: 1.5566x; 1.0155x over previous
//
#include <hip/hip_runtime.h>

typedef float  f32x16 __attribute__((ext_vector_type(16)));
typedef short  short8 __attribute__((ext_vector_type(8)));
typedef unsigned short u16;
typedef unsigned int   u32;

#define LOG2PI_F 1.8378770664093453f

__device__ __forceinline__ u16 f2bf(float f) {
  u32 u = __builtin_bit_cast(u32, f);
  u32 r = (u + 0x7FFFu + ((u >> 16) & 1u)) >> 16;
  return (u16)r;
}

// ---------------------------------------------------------------------------
// K0: emissions. E[t,j] = exp(log_em[t,j] - s_t), s_t = max_j log_em[t,j].
// ---------------------------------------------------------------------------
__global__ __launch_bounds__(256) void emis_kernel(
    const float* __restrict__ Y, const float* __restrict__ mu,
    const float* __restrict__ rlv, int T,
    float* __restrict__ E, float* __restrict__ Spart)
{
  int j  = threadIdx.x & 31;
  int ts = threadIdx.x >> 5;  // 0..7

  float muv[16], iv[16];
  float slv = 0.f;
  const float4* mp = (const float4*)(mu  + (size_t)j * 16);
  const float4* rp = (const float4*)(rlv + (size_t)j * 16);
#pragma unroll
  for (int q = 0; q < 4; ++q) {
    float4 m4 = mp[q], r4 = rp[q];
    float mm[4] = {m4.x, m4.y, m4.z, m4.w};
    float rr[4] = {r4.x, r4.y, r4.z, r4.w};
#pragma unroll
    for (int e = 0; e < 4; ++e) {
      float lv = fminf(fmaxf(rr[e], -6.f), 6.f);
      muv[4*q+e] = mm[e];
      iv[4*q+e]  = __expf(-lv);
      slv += lv;
    }
  }
  float base_c = 16.f * LOG2PI_F + slv;

  float sacc = 0.f;
  for (int p2 = 0; p2 < 8; ++p2) {
    int t = blockIdx.x * 64 + p2 * 8 + ts;
    if (t < T) {
      float quad = 0.f;
      const float4* yp = (const float4*)(Y + (size_t)t * 16);
#pragma unroll
      for (int q = 0; q < 4; ++q) {
        float4 y4 = yp[q];
        float yy[4] = {y4.x, y4.y, y4.z, y4.w};
#pragma unroll
        for (int e = 0; e < 4; ++e) {
          float d = yy[e] - muv[4*q+e];
          quad = fmaf(d * d, iv[4*q+e], quad);
        }
      }
      float lem = -0.5f * (base_c + quad);
      float mx = lem;
#pragma unroll
      for (int m = 16; m >= 1; m >>= 1) mx = fmaxf(mx, __shfl_xor(mx, m, 32));
      E[(size_t)t * 32 + j] = __expf(lem - mx);
      if (j == 0) sacc += mx;
    }
  }
  __shared__ float sred[8];
  if (j == 0) sred[ts] = sacc;
  __syncthreads();
  if (threadIdx.x == 0) {
    float s = 0.f;
#pragma unroll
    for (int k = 0; k < 8; ++k) s += sred[k];
    Spart[blockIdx.x] = s;
  }
}

// ---------------------------------------------------------------------------
// Prep: Wfrag = A-operand fragments of W/ln2 (bf16), bprime = b/ln2.
// ---------------------------------------------------------------------------
__global__ __launch_bounds__(256) void prep_kernel(
    const float* __restrict__ W, const float* __restrict__ b,
    u16* __restrict__ Wfrag, float* __restrict__ bprime)
{
  const float INVLN2 = 1.4426950408889634f;
  int idx = blockIdx.x * 256 + threadIdx.x;
  if (idx < 16384) {
    int i = idx >> 9, rem = idx & 511, l = rem >> 3, e = rem & 7;
    int j = l & 31, h = l >> 5;
    Wfrag[idx] = f2bf(W[i * 512 + j * 16 + h * 8 + e] * INVLN2);
  }
  if (idx < 1024) bprime[idx] = b[idx] * INVLN2;
}

// ---------------------------------------------------------------------------
// Shared primitives (hardware-verified rounds 0-2).
// ---------------------------------------------------------------------------
__device__ __forceinline__ void acc_to_bops(const f32x16& acc, uint4& B1, uint4& B2) {
  u32 pk[8];
#pragma unroll
  for (int q = 0; q < 8; ++q) {
    u32 r;
    asm("v_cvt_pk_bf16_f32 %0, %1, %2" : "=v"(r) : "v"(acc[2*q]), "v"(acc[2*q+1]));
    pk[q] = r;
  }
  asm("v_permlane32_swap_b32 %0, %1" : "+v"(pk[0]), "+v"(pk[2]));
  asm("v_permlane32_swap_b32 %0, %1" : "+v"(pk[1]), "+v"(pk[3]));
  B1 = make_uint4(pk[0], pk[1], pk[2], pk[3]);
  asm("v_permlane32_swap_b32 %0, %1" : "+v"(pk[4]), "+v"(pk[6]));
  asm("v_permlane32_swap_b32 %0, %1" : "+v"(pk[5]), "+v"(pk[7]));
  B2 = make_uint4(pk[4], pk[5], pk[6], pk[7]);
}

__device__ __forceinline__ void renorm(f32x16& acc, float& Eacc) {
  float m = acc[0];
#pragma unroll
  for (int r = 1; r < 16; ++r) m = fmaxf(m, acc[r]);
#pragma unroll
  for (int off = 32; off >= 1; off >>= 1) m = fmaxf(m, __shfl_xor(m, off, 64));
  if (m > 0.f) {
    int ex;
    frexpf(m, &ex);
    float sc = ldexpf(1.f, -ex);
#pragma unroll
    for (int r = 0; r < 16; ++r) acc[r] *= sc;
    Eacc += (float)ex;
  }
}

__device__ __forceinline__ void bmat2_batch(
    const short8* wf, int ib0, short8 xf, const float* __restrict__ bprime,
    int h, const float* ee, u32* cw /* [32] */)
{
  f32x16 a[4];
#pragma unroll
  for (int e = 0; e < 4; ++e) {
    f32x16 c;
#pragma unroll
    for (int qd = 0; qd < 4; ++qd) {
      float4 b4 = *(const float4*)(bprime + (ib0 + e) * 32 + 4 * h + 8 * qd);
      c[4*qd+0] = b4.x; c[4*qd+1] = b4.y; c[4*qd+2] = b4.z; c[4*qd+3] = b4.w;
    }
    a[e] = __builtin_amdgcn_mfma_f32_32x32x16_bf16(wf[e], xf, c, 0, 0, 0);
  }
#pragma unroll
  for (int e = 0; e < 4; ++e) {
    float s = 0.f;
#pragma unroll
    for (int r = 0; r < 16; ++r) { float p = exp2f(a[e][r]); a[e][r] = p; s += p; }
    float s2 = s, s3 = s;
    asm("v_permlane32_swap_b32 %0, %1" : "+v"(s2), "+v"(s3));
    float rv = __builtin_amdgcn_rcpf(s2 + s3);
#pragma unroll
    for (int r = 0; r < 16; ++r) a[e][r] *= rv;
  }
#pragma unroll
  for (int r = 0; r < 16; ++r) {
    float e0 = a[0][r] * ee[r], e1 = a[1][r] * ee[r];
    float e2 = a[2][r] * ee[r], e3 = a[3][r] * ee[r];
    u32 w0, w1;
    asm("v_cvt_pk_bf16_f32 %0, %1, %2" : "=v"(w0) : "v"(e0), "v"(e1));
    asm("v_cvt_pk_bf16_f32 %0, %1, %2" : "=v"(w1) : "v"(e2), "v"(e3));
    cw[r*2+0] = w0; cw[r*2+1] = w1;
  }
}

// ---------------------------------------------------------------------------
// bmat2: identical math to verified round-2 kernel; ONLY the Bseg addressing
// changed to chunk-major (transposed): chunk c of matrix trel at uint4 index
// c*TSEG + trel. Per store instruction, the 32 t-lanes are consecutive uint4s
// -> two fully-coalesced 512B segments (was: 32 scattered 16B chunks).
// ---------------------------------------------------------------------------
__global__ __launch_bounds__(256, 2) void bmat2_kernel(
    const float* __restrict__ X, const float* __restrict__ E,
    const u16* __restrict__ Wfrag, const float* __restrict__ bprime,
    int T, int seg_t0, int tn, int TSEG, uint4* __restrict__ Bseg2)
{
  int tid = threadIdx.x;
  int w = tid >> 6, l = tid & 63, tc = l & 31, h = l >> 5;

  short8 wf[8];
#pragma unroll
  for (int it = 0; it < 8; ++it)
    wf[it] = *(const short8*)(Wfrag + ((size_t)(8*w + it) * 64 + l) * 8);

  for (int gi = 0; gi < 4; ++gi) {
    int trel0 = blockIdx.x * 128 + gi * 32;
    if (trel0 >= tn) return;
    int trel = trel0 + tc;
    int tglob = seg_t0 + trel;

    float4 xa = *(const float4*)(X + (size_t)tglob * 16 + 8 * h);
    float4 xb = *(const float4*)(X + (size_t)tglob * 16 + 8 * h + 4);
    u32 xp0, xp1, xp2, xp3;
    asm("v_cvt_pk_bf16_f32 %0, %1, %2" : "=v"(xp0) : "v"(xa.x), "v"(xa.y));
    asm("v_cvt_pk_bf16_f32 %0, %1, %2" : "=v"(xp1) : "v"(xa.z), "v"(xa.w));
    asm("v_cvt_pk_bf16_f32 %0, %1, %2" : "=v"(xp2) : "v"(xb.x), "v"(xb.y));
    asm("v_cvt_pk_bf16_f32 %0, %1, %2" : "=v"(xp3) : "v"(xb.z), "v"(xb.w));
    uint4 xu = make_uint4(xp0, xp1, xp2, xp3);
    short8 xf = __builtin_bit_cast(short8, xu);

    float ee[16];
#pragma unroll
    for (int qd = 0; qd < 4; ++qd) {
      float4 eq = *(const float4*)(E + (size_t)tglob * 32 + 4 * h + 8 * qd);
      ee[4*qd+0] = eq.x; ee[4*qd+1] = eq.y; ee[4*qd+2] = eq.z; ee[4*qd+3] = eq.w;
    }

    u32 cA[32], cB[32];
    bmat2_batch(wf,     8*w,     xf, bprime, h, ee, cA);
    bmat2_batch(wf + 4, 8*w + 4, xf, bprime, h, ee, cB);

#pragma unroll
    for (int qd = 0; qd < 4; ++qd) {
#pragma unroll
      for (int pp = 0; pp < 4; ++pp) {
        int r = 4*qd + pp;
        int j = 4*h + 8*qd + pp;
        uint4 v = make_uint4(cA[2*r], cA[2*r+1], cB[2*r], cB[2*r+1]);
        if (tglob == 0) {
          u32 i0 = 8*w;
          u32 w0 = ((i0+0 == (u32)j) ? 0x3F80u : 0u) | (((i0+1 == (u32)j) ? 0x3F80u : 0u) << 16);
          u32 w1 = ((i0+2 == (u32)j) ? 0x3F80u : 0u) | (((i0+3 == (u32)j) ? 0x3F80u : 0u) << 16);
          u32 w2 = ((i0+4 == (u32)j) ? 0x3F80u : 0u) | (((i0+5 == (u32)j) ? 0x3F80u : 0u) << 16);
          u32 w3 = ((i0+6 == (u32)j) ? 0x3F80u : 0u) | (((i0+7 == (u32)j) ? 0x3F80u : 0u) << 16);
          v = make_uint4(w0, w1, w2, w3);
        }
        size_t c = (size_t)((j + 32 * (w & 1)) * 2 + (w >> 1));
        Bseg2[c * (size_t)TSEG + (size_t)trel] = v;
      }
    }
  }
}

// ---------------------------------------------------------------------------
// Chain kernel (verified math). Generic addressing: chunk c of matrix m at
// uint4 index c*CC + m*MS.  Level 1 (transposed Bseg2): CC=TSEG, MS=1 — each
// lane's 8-matrix group is a contiguous 128B line.  Levels 2-3 (matrix-major
// Sg/Rf, exact round-2 layout): CC=1, MS=128.
// ---------------------------------------------------------------------------
__global__ __launch_bounds__(64) void chain_kernel(
    const uint4* __restrict__ in_frags, const float* __restrict__ in_E,
    int mpb, long CC, long MS, u16* __restrict__ out_frags,
    float* __restrict__ out_E, float* __restrict__ out_final)
{
  int l = threadIdx.x;
  long base = (long)blockIdx.x * mpb;
  const uint4* pA = in_frags + (size_t)(2 * l) * CC + (size_t)base * MS;
  const uint4* pB = pA + CC;

  uint4 bufA[8], bufB[8];
#pragma unroll
  for (int u = 0; u < 8; ++u) {
    bufA[u] = pA[(size_t)u * MS];
    bufB[u] = pB[(size_t)u * MS];
  }

  int col = l & 31, h = l >> 5;
  f32x16 acc, zero16;
#pragma unroll
  for (int r = 0; r < 16; ++r) {
    int row = (r & 3) + 8 * (r >> 2) + 4 * h;
    acc[r]  = (row == col) ? 1.f : 0.f;
    zero16[r] = 0.f;
  }

  float Eacc = 0.f;
  if (in_E) {
    for (int k = 0; k < mpb; ++k) Eacc += in_E[base + k];
  }

  for (int s = 0; s < mpb; s += 8) {
#pragma unroll
    for (int u = 0; u < 8; ++u) {
      uint4 B1, B2;
      acc_to_bops(acc, B1, B2);
      short8 A1 = __builtin_bit_cast(short8, bufA[u]);
      short8 A2 = __builtin_bit_cast(short8, bufB[u]);
      int nm = s + u + 8;
      if (nm < mpb) {
        bufA[u] = pA[(size_t)nm * MS];
        bufB[u] = pB[(size_t)nm * MS];
      }
      f32x16 t1 = __builtin_amdgcn_mfma_f32_32x32x16_bf16(
          A1, __builtin_bit_cast(short8, B1), zero16, 0, 0, 0);
      acc = __builtin_amdgcn_mfma_f32_32x32x16_bf16(
          A2, __builtin_bit_cast(short8, B2), t1, 0, 0, 0);
    }
    renorm(acc, Eacc);
  }

  if (out_final) {
#pragma unroll
    for (int r = 0; r < 16; ++r) {
      int row = (r & 3) + 8 * (r >> 2) + 4 * h;
      out_final[row * 32 + col] = acc[r];
    }
    if (l == 0) *out_E = Eacc;
  } else {
#pragma unroll
    for (int r = 0; r < 16; ++r) {
      int row = (r & 3) + 8 * (r >> 2) + 4 * h;
      int flat = (row + 32 * ((col >> 3) & 1)) * 16 + ((col >> 4) << 3) + (col & 7);
      out_frags[(size_t)blockIdx.x * 1024 + flat] = f2bf(acc[r]);
    }
    if (l == 0) out_E[blockIdx.x] = Eacc;
  }
}

// ---------------------------------------------------------------------------
// finalize (unchanged, verified).
// ---------------------------------------------------------------------------
__global__ __launch_bounds__(64) void finalize_kernel(
    const float* __restrict__ init_logits, const float* __restrict__ E,
    const float* __restrict__ Spart, int nSpart,
    const float* __restrict__ MT, const float* __restrict__ Egrand,
    float* __restrict__ out)
{
  int l = threadIdx.x;
  int j = l & 31;

  float il = init_logits[j];
  float mx = il;
#pragma unroll
  for (int m = 16; m >= 1; m >>= 1) mx = fmaxf(mx, __shfl_xor(mx, m, 32));
  float pz = __expf(il - mx);
  float sz = pz;
#pragma unroll
  for (int m = 16; m >= 1; m >>= 1) sz += __shfl_xor(sz, m, 32);
  float a0 = (pz / sz) * E[j];

  float rbuf[32];
  const float4* rowp = (const float4*)(MT + j * 32);
#pragma unroll
  for (int q = 0; q < 8; ++q) {
    float4 v = rowp[q];
    rbuf[4*q+0] = v.x; rbuf[4*q+1] = v.y; rbuf[4*q+2] = v.z; rbuf[4*q+3] = v.w;
  }
  float af = 0.f;
#pragma unroll
  for (int m = 0; m < 32; ++m) af = fmaf(__shfl(a0, m, 32), rbuf[m], af);

  float sa = af;
#pragma unroll
  for (int m = 16; m >= 1; m >>= 1) sa += __shfl_xor(sa, m, 32);

  double ss = 0.0;
  for (int idx = l; idx < nSpart; idx += 64) ss += (double)Spart[idx];
#pragma unroll
  for (int m = 32; m >= 1; m >>= 1) ss += __shfl_xor(ss, m, 64);

  if (l == 0) {
    double r = log((double)sa) + ss + 0.6931471805599453 * (double)(*Egrand);
    out[0] = (float)r;
  }
}

// ---------------------------------------------------------------------------
extern "C" void kernel_launch(void* const* d_in, const int* in_sizes, int n_in,
                              void* d_out, int out_size, void* d_ws, size_t ws_size,
                              hipStream_t stream) {
  const float* X   = (const float*)d_in[0];
  const float* Y   = (const float*)d_in[1];
  const float* il  = (const float*)d_in[2];
  const float* W   = (const float*)d_in[3];
  const float* b   = (const float*)d_in[4];
  const float* mu  = (const float*)d_in[5];
  const float* rlv = (const float*)d_in[6];
  float* out = (float*)d_out;

  int T   = in_sizes[0] / 16;
  int NB0 = (T + 63) / 64;
  int NB2 = T / 64;  // T = 131072: multiple of 64

  char* ws = (char*)d_ws;
  size_t off = 0;
  auto alloc = [&](size_t bytes) -> void* {
    void* p = ws + off;
    off = (off + bytes + 255) & ~(size_t)255;
    return p;
  };
  float* E      = (float*)alloc((size_t)T * 32 * 4);
  float* Spart  = (float*)alloc((size_t)NB0 * 4);
  u16*   Sg     = (u16*)  alloc((size_t)NB2 * 2048);
  float* Eg     = (float*)alloc((size_t)NB2 * 4);
  u16*   Rf     = (u16*)  alloc((size_t)64 * 2048);
  float* ER     = (float*)alloc((size_t)64 * 4);
  float* MT     = (float*)alloc(4096);
  float* Egrand = (float*)alloc(256);
  u16*   Wfrag  = (u16*)  alloc((size_t)16384 * 2);
  float* bprime = (float*)alloc((size_t)1024 * 4);

  size_t avail = (ws_size > off) ? (ws_size - off) : 0;
  long tseg = (long)(avail / 2048) & ~63L;
  if (tseg < 64) tseg = 64;
  if (tseg > T) tseg = T;
  int TSEG = (int)tseg;
  uint4* Bseg2 = (uint4*)(ws + off);

  prep_kernel<<<64, 256, 0, stream>>>(W, b, Wfrag, bprime);
  emis_kernel<<<NB0, 256, 0, stream>>>(Y, mu, rlv, T, E, Spart);

  for (int t0 = 0; t0 < T; t0 += TSEG) {
    int tn = (T - t0 < TSEG) ? (T - t0) : TSEG;
    int nblk = (tn + 127) / 128;
    bmat2_kernel<<<nblk, 256, 0, stream>>>(X, E, Wfrag, bprime, T, t0, tn, TSEG, Bseg2);
    int bps = tn / 64;
    chain_kernel<<<bps, 64, 0, stream>>>(
        Bseg2, nullptr, 64, (long)TSEG, 1L,
        Sg + (size_t)(t0 / 64) * 1024, Eg + t0 / 64, nullptr);
  }

  int mpb1 = NB2 / 64;  // 32
  chain_kernel<<<64, 64, 0, stream>>>((const uint4*)Sg, Eg, mpb1, 1L, 128L, Rf, ER, nullptr);
  chain_kernel<<<1, 64, 0, stream>>>((const uint4*)Rf, ER, 64, 1L, 128L, nullptr, Egrand, MT);

  finalize_kernel<<<1, 64, 0, stream>>>(il, E, Spart, NB0, MT, Egrand, out);
}

// Round 7
// 229.458 us; speedup vs baseline: 1.6769x; 1.0773x over previous
//
#include <hip/hip_runtime.h>

typedef float  f32x16 __attribute__((ext_vector_type(16)));
typedef short  short8 __attribute__((ext_vector_type(8)));
typedef unsigned short u16;
typedef unsigned int   u32;

#define LOG2PI_F 1.8378770664093453f

__device__ __forceinline__ u16 f2bf(float f) {
  u32 u = __builtin_bit_cast(u32, f);
  u32 r = (u + 0x7FFFu + ((u >> 16) & 1u)) >> 16;
  return (u16)r;
}

// ---------------------------------------------------------------------------
// K0: emissions. E[t,j] = exp(log_em[t,j] - s_t), s_t = max_j log_em[t,j].
// ---------------------------------------------------------------------------
__global__ __launch_bounds__(256) void emis_kernel(
    const float* __restrict__ Y, const float* __restrict__ mu,
    const float* __restrict__ rlv, int T,
    float* __restrict__ E, float* __restrict__ Spart)
{
  int j  = threadIdx.x & 31;
  int ts = threadIdx.x >> 5;  // 0..7

  float muv[16], iv[16];
  float slv = 0.f;
  const float4* mp = (const float4*)(mu  + (size_t)j * 16);
  const float4* rp = (const float4*)(rlv + (size_t)j * 16);
#pragma unroll
  for (int q = 0; q < 4; ++q) {
    float4 m4 = mp[q], r4 = rp[q];
    float mm[4] = {m4.x, m4.y, m4.z, m4.w};
    float rr[4] = {r4.x, r4.y, r4.z, r4.w};
#pragma unroll
    for (int e = 0; e < 4; ++e) {
      float lv = fminf(fmaxf(rr[e], -6.f), 6.f);
      muv[4*q+e] = mm[e];
      iv[4*q+e]  = __expf(-lv);
      slv += lv;
    }
  }
  float base_c = 16.f * LOG2PI_F + slv;

  float sacc = 0.f;
  for (int p2 = 0; p2 < 8; ++p2) {
    int t = blockIdx.x * 64 + p2 * 8 + ts;
    if (t < T) {
      float quad = 0.f;
      const float4* yp = (const float4*)(Y + (size_t)t * 16);
#pragma unroll
      for (int q = 0; q < 4; ++q) {
        float4 y4 = yp[q];
        float yy[4] = {y4.x, y4.y, y4.z, y4.w};
#pragma unroll
        for (int e = 0; e < 4; ++e) {
          float d = yy[e] - muv[4*q+e];
          quad = fmaf(d * d, iv[4*q+e], quad);
        }
      }
      float lem = -0.5f * (base_c + quad);
      float mx = lem;
#pragma unroll
      for (int m = 16; m >= 1; m >>= 1) mx = fmaxf(mx, __shfl_xor(mx, m, 32));
      E[(size_t)t * 32 + j] = __expf(lem - mx);
      if (j == 0) sacc += mx;
    }
  }
  __shared__ float sred[8];
  if (j == 0) sred[ts] = sacc;
  __syncthreads();
  if (threadIdx.x == 0) {
    float s = 0.f;
#pragma unroll
    for (int k = 0; k < 8; ++k) s += sred[k];
    Spart[blockIdx.x] = s;
  }
}

// ---------------------------------------------------------------------------
// Prep: Wfrag = A-operand fragments of W/ln2 (bf16), bprime = b/ln2.
// ---------------------------------------------------------------------------
__global__ __launch_bounds__(256) void prep_kernel(
    const float* __restrict__ W, const float* __restrict__ b,
    u16* __restrict__ Wfrag, float* __restrict__ bprime)
{
  const float INVLN2 = 1.4426950408889634f;
  int idx = blockIdx.x * 256 + threadIdx.x;
  if (idx < 16384) {
    int i = idx >> 9, rem = idx & 511, l = rem >> 3, e = rem & 7;
    int j = l & 31, h = l >> 5;
    Wfrag[idx] = f2bf(W[i * 512 + j * 16 + h * 8 + e] * INVLN2);
  }
  if (idx < 1024) bprime[idx] = b[idx] * INVLN2;
}

// ---------------------------------------------------------------------------
// Shared primitives (hardware-verified rounds 0-5).
// ---------------------------------------------------------------------------
__device__ __forceinline__ void acc_to_bops(const f32x16& acc, uint4& B1, uint4& B2) {
  u32 pk[8];
#pragma unroll
  for (int q = 0; q < 8; ++q) {
    u32 r;
    asm("v_cvt_pk_bf16_f32 %0, %1, %2" : "=v"(r) : "v"(acc[2*q]), "v"(acc[2*q+1]));
    pk[q] = r;
  }
  asm("v_permlane32_swap_b32 %0, %1" : "+v"(pk[0]), "+v"(pk[2]));
  asm("v_permlane32_swap_b32 %0, %1" : "+v"(pk[1]), "+v"(pk[3]));
  B1 = make_uint4(pk[0], pk[1], pk[2], pk[3]);
  asm("v_permlane32_swap_b32 %0, %1" : "+v"(pk[4]), "+v"(pk[6]));
  asm("v_permlane32_swap_b32 %0, %1" : "+v"(pk[5]), "+v"(pk[7]));
  B2 = make_uint4(pk[4], pk[5], pk[6], pk[7]);
}

__device__ __forceinline__ void renorm(f32x16& acc, float& Eacc) {
  float m = acc[0];
#pragma unroll
  for (int r = 1; r < 16; ++r) m = fmaxf(m, acc[r]);
#pragma unroll
  for (int off = 32; off >= 1; off >>= 1) m = fmaxf(m, __shfl_xor(m, off, 64));
  if (m > 0.f) {
    int ex;
    frexpf(m, &ex);
    float sc = ldexpf(1.f, -ex);
#pragma unroll
    for (int r = 0; r < 16; ++r) acc[r] *= sc;
    Eacc += (float)ex;
  }
}

__device__ __forceinline__ void bmat2_batch(
    const short8* wf, int ib0, short8 xf, const float* __restrict__ bprime,
    int h, const float* ee, u32* cw /* [32] */)
{
  f32x16 a[4];
#pragma unroll
  for (int e = 0; e < 4; ++e) {
    f32x16 c;
#pragma unroll
    for (int qd = 0; qd < 4; ++qd) {
      float4 b4 = *(const float4*)(bprime + (ib0 + e) * 32 + 4 * h + 8 * qd);
      c[4*qd+0] = b4.x; c[4*qd+1] = b4.y; c[4*qd+2] = b4.z; c[4*qd+3] = b4.w;
    }
    a[e] = __builtin_amdgcn_mfma_f32_32x32x16_bf16(wf[e], xf, c, 0, 0, 0);
  }
#pragma unroll
  for (int e = 0; e < 4; ++e) {
    float s = 0.f;
#pragma unroll
    for (int r = 0; r < 16; ++r) { float p = exp2f(a[e][r]); a[e][r] = p; s += p; }
    float s2 = s, s3 = s;
    asm("v_permlane32_swap_b32 %0, %1" : "+v"(s2), "+v"(s3));
    float rv = __builtin_amdgcn_rcpf(s2 + s3);
#pragma unroll
    for (int r = 0; r < 16; ++r) a[e][r] *= rv;
  }
#pragma unroll
  for (int r = 0; r < 16; ++r) {
    float e0 = a[0][r] * ee[r], e1 = a[1][r] * ee[r];
    float e2 = a[2][r] * ee[r], e3 = a[3][r] * ee[r];
    u32 w0, w1;
    asm("v_cvt_pk_bf16_f32 %0, %1, %2" : "=v"(w0) : "v"(e0), "v"(e1));
    asm("v_cvt_pk_bf16_f32 %0, %1, %2" : "=v"(w1) : "v"(e2), "v"(e3));
    cw[r*2+0] = w0; cw[r*2+1] = w1;
  }
}

// ---------------------------------------------------------------------------
// bmat2 (verbatim green round-5 kernel): chunk-major transposed Bseg2 —
// chunk c of matrix trel at uint4 index c*TSEG + trel. Coalesced stores.
// ---------------------------------------------------------------------------
__global__ __launch_bounds__(256, 2) void bmat2_kernel(
    const float* __restrict__ X, const float* __restrict__ E,
    const u16* __restrict__ Wfrag, const float* __restrict__ bprime,
    int T, int seg_t0, int tn, int TSEG, uint4* __restrict__ Bseg2)
{
  int tid = threadIdx.x;
  int w = tid >> 6, l = tid & 63, tc = l & 31, h = l >> 5;

  short8 wf[8];
#pragma unroll
  for (int it = 0; it < 8; ++it)
    wf[it] = *(const short8*)(Wfrag + ((size_t)(8*w + it) * 64 + l) * 8);

  for (int gi = 0; gi < 4; ++gi) {
    int trel0 = blockIdx.x * 128 + gi * 32;
    if (trel0 >= tn) return;
    int trel = trel0 + tc;
    int tglob = seg_t0 + trel;

    float4 xa = *(const float4*)(X + (size_t)tglob * 16 + 8 * h);
    float4 xb = *(const float4*)(X + (size_t)tglob * 16 + 8 * h + 4);
    u32 xp0, xp1, xp2, xp3;
    asm("v_cvt_pk_bf16_f32 %0, %1, %2" : "=v"(xp0) : "v"(xa.x), "v"(xa.y));
    asm("v_cvt_pk_bf16_f32 %0, %1, %2" : "=v"(xp1) : "v"(xa.z), "v"(xa.w));
    asm("v_cvt_pk_bf16_f32 %0, %1, %2" : "=v"(xp2) : "v"(xb.x), "v"(xb.y));
    asm("v_cvt_pk_bf16_f32 %0, %1, %2" : "=v"(xp3) : "v"(xb.z), "v"(xb.w));
    uint4 xu = make_uint4(xp0, xp1, xp2, xp3);
    short8 xf = __builtin_bit_cast(short8, xu);

    float ee[16];
#pragma unroll
    for (int qd = 0; qd < 4; ++qd) {
      float4 eq = *(const float4*)(E + (size_t)tglob * 32 + 4 * h + 8 * qd);
      ee[4*qd+0] = eq.x; ee[4*qd+1] = eq.y; ee[4*qd+2] = eq.z; ee[4*qd+3] = eq.w;
    }

    u32 cA[32], cB[32];
    bmat2_batch(wf,     8*w,     xf, bprime, h, ee, cA);
    bmat2_batch(wf + 4, 8*w + 4, xf, bprime, h, ee, cB);

#pragma unroll
    for (int qd = 0; qd < 4; ++qd) {
#pragma unroll
      for (int pp = 0; pp < 4; ++pp) {
        int r = 4*qd + pp;
        int j = 4*h + 8*qd + pp;
        uint4 v = make_uint4(cA[2*r], cA[2*r+1], cB[2*r], cB[2*r+1]);
        if (tglob == 0) {
          u32 i0 = 8*w;
          u32 w0 = ((i0+0 == (u32)j) ? 0x3F80u : 0u) | (((i0+1 == (u32)j) ? 0x3F80u : 0u) << 16);
          u32 w1 = ((i0+2 == (u32)j) ? 0x3F80u : 0u) | (((i0+3 == (u32)j) ? 0x3F80u : 0u) << 16);
          u32 w2 = ((i0+4 == (u32)j) ? 0x3F80u : 0u) | (((i0+5 == (u32)j) ? 0x3F80u : 0u) << 16);
          u32 w3 = ((i0+6 == (u32)j) ? 0x3F80u : 0u) | (((i0+7 == (u32)j) ? 0x3F80u : 0u) << 16);
          v = make_uint4(w0, w1, w2, w3);
        }
        size_t c = (size_t)((j + 32 * (w & 1)) * 2 + (w >> 1));
        Bseg2[c * (size_t)TSEG + (size_t)trel] = v;
      }
    }
  }
}

// ---------------------------------------------------------------------------
// Chain kernel (verified math, round-5 addressing). Now multi-wave: each wave
// of the block runs one independent chain cid = blockIdx*(blockDim/64) + w.
// No __syncthreads anywhere -> multi-wave safe. Generic addressing: chunk c of
// matrix m at uint4 index c*CC + m*MS. L1 (chunk-major Bseg2): CC=TSEG, MS=1.
// Levels 2-3 (matrix-major): CC=1, MS=128.
// ---------------------------------------------------------------------------
__global__ void chain_kernel(
    const uint4* __restrict__ in_frags, const float* __restrict__ in_E,
    int nchains, int mpb, long CC, long MS, u16* __restrict__ out_frags,
    float* __restrict__ out_E, float* __restrict__ out_final)
{
  int w = threadIdx.x >> 6, l = threadIdx.x & 63;
  int cid = blockIdx.x * (blockDim.x >> 6) + w;
  if (cid >= nchains) return;

  long base = (long)cid * mpb;
  const uint4* pA = in_frags + (size_t)(2 * l) * CC + (size_t)base * MS;
  const uint4* pB = pA + CC;

  uint4 bufA[8], bufB[8];
#pragma unroll
  for (int u = 0; u < 8; ++u) {
    bufA[u] = pA[(size_t)u * MS];
    bufB[u] = pB[(size_t)u * MS];
  }

  int col = l & 31, h = l >> 5;
  f32x16 acc, zero16;
#pragma unroll
  for (int r = 0; r < 16; ++r) {
    int row = (r & 3) + 8 * (r >> 2) + 4 * h;
    acc[r]  = (row == col) ? 1.f : 0.f;
    zero16[r] = 0.f;
  }

  float Eacc = 0.f;
  if (in_E) {
    for (int k = 0; k < mpb; ++k) Eacc += in_E[base + k];
  }

  for (int s = 0; s < mpb; s += 8) {
#pragma unroll
    for (int u = 0; u < 8; ++u) {
      uint4 B1, B2;
      acc_to_bops(acc, B1, B2);
      short8 A1 = __builtin_bit_cast(short8, bufA[u]);
      short8 A2 = __builtin_bit_cast(short8, bufB[u]);
      int nm = s + u + 8;
      if (nm < mpb) {
        bufA[u] = pA[(size_t)nm * MS];
        bufB[u] = pB[(size_t)nm * MS];
      }
      f32x16 t1 = __builtin_amdgcn_mfma_f32_32x32x16_bf16(
          A1, __builtin_bit_cast(short8, B1), zero16, 0, 0, 0);
      acc = __builtin_amdgcn_mfma_f32_32x32x16_bf16(
          A2, __builtin_bit_cast(short8, B2), t1, 0, 0, 0);
    }
    renorm(acc, Eacc);
  }

  if (out_final) {
#pragma unroll
    for (int r = 0; r < 16; ++r) {
      int row = (r & 3) + 8 * (r >> 2) + 4 * h;
      out_final[row * 32 + col] = acc[r];
    }
    if (l == 0) *out_E = Eacc;
  } else {
#pragma unroll
    for (int r = 0; r < 16; ++r) {
      int row = (r & 3) + 8 * (r >> 2) + 4 * h;
      int flat = (row + 32 * ((col >> 3) & 1)) * 16 + ((col >> 4) << 3) + (col & 7);
      out_frags[(size_t)cid * 1024 + flat] = f2bf(acc[r]);
    }
    if (l == 0) out_E[cid] = Eacc;
  }
}

// ---------------------------------------------------------------------------
// finalize (unchanged, verified).
// ---------------------------------------------------------------------------
__global__ __launch_bounds__(64) void finalize_kernel(
    const float* __restrict__ init_logits, const float* __restrict__ E,
    const float* __restrict__ Spart, int nSpart,
    const float* __restrict__ MT, const float* __restrict__ Egrand,
    float* __restrict__ out)
{
  int l = threadIdx.x;
  int j = l & 31;

  float il = init_logits[j];
  float mx = il;
#pragma unroll
  for (int m = 16; m >= 1; m >>= 1) mx = fmaxf(mx, __shfl_xor(mx, m, 32));
  float pz = __expf(il - mx);
  float sz = pz;
#pragma unroll
  for (int m = 16; m >= 1; m >>= 1) sz += __shfl_xor(sz, m, 32);
  float a0 = (pz / sz) * E[j];

  float rbuf[32];
  const float4* rowp = (const float4*)(MT + j * 32);
#pragma unroll
  for (int q = 0; q < 8; ++q) {
    float4 v = rowp[q];
    rbuf[4*q+0] = v.x; rbuf[4*q+1] = v.y; rbuf[4*q+2] = v.z; rbuf[4*q+3] = v.w;
  }
  float af = 0.f;
#pragma unroll
  for (int m = 0; m < 32; ++m) af = fmaf(__shfl(a0, m, 32), rbuf[m], af);

  float sa = af;
#pragma unroll
  for (int m = 16; m >= 1; m >>= 1) sa += __shfl_xor(sa, m, 32);

  double ss = 0.0;
  for (int idx = l; idx < nSpart; idx += 64) ss += (double)Spart[idx];
#pragma unroll
  for (int m = 32; m >= 1; m >>= 1) ss += __shfl_xor(ss, m, 64);

  if (l == 0) {
    double r = log((double)sa) + ss + 0.6931471805599453 * (double)(*Egrand);
    out[0] = (float)r;
  }
}

// ---------------------------------------------------------------------------
extern "C" void kernel_launch(void* const* d_in, const int* in_sizes, int n_in,
                              void* d_out, int out_size, void* d_ws, size_t ws_size,
                              hipStream_t stream) {
  const float* X   = (const float*)d_in[0];
  const float* Y   = (const float*)d_in[1];
  const float* il  = (const float*)d_in[2];
  const float* W   = (const float*)d_in[3];
  const float* b   = (const float*)d_in[4];
  const float* mu  = (const float*)d_in[5];
  const float* rlv = (const float*)d_in[6];
  float* out = (float*)d_out;

  int T   = in_sizes[0] / 16;
  int NB0 = (T + 63) / 64;
  int NC1 = T / 32;   // L1 chains total (4096 @ T=131072)

  char* ws = (char*)d_ws;
  size_t off = 0;
  auto alloc = [&](size_t bytes) -> void* {
    void* p = ws + off;
    off = (off + bytes + 255) & ~(size_t)255;
    return p;
  };
  float* E      = (float*)alloc((size_t)T * 32 * 4);
  float* Spart  = (float*)alloc((size_t)NB0 * 4);
  u16*   Sg     = (u16*)  alloc((size_t)NC1 * 2048);
  float* Eg     = (float*)alloc((size_t)NC1 * 4);
  u16*   Rf     = (u16*)  alloc((size_t)64 * 2048);
  float* ER     = (float*)alloc((size_t)64 * 4);
  float* MT     = (float*)alloc(4096);
  float* Egrand = (float*)alloc(256);
  u16*   Wfrag  = (u16*)  alloc((size_t)16384 * 2);
  float* bprime = (float*)alloc((size_t)1024 * 4);

  size_t avail = (ws_size > off) ? (ws_size - off) : 0;
  long tseg = (long)(avail / 2048) & ~127L;   // multiple of 128
  if (tseg < 128) tseg = 128;
  if (tseg > 65536) tseg = 65536;             // keep Bseg L3-resident (128 MB)
  if (tseg > T) tseg = T;
  int TSEG = (int)tseg;
  uint4* Bseg2 = (uint4*)(ws + off);

  prep_kernel<<<64, 256, 0, stream>>>(W, b, Wfrag, bprime);
  emis_kernel<<<NB0, 256, 0, stream>>>(Y, mu, rlv, T, E, Spart);

  for (int t0 = 0; t0 < T; t0 += TSEG) {
    int tn = (T - t0 < TSEG) ? (T - t0) : TSEG;   // multiple of 128
    int nblk = (tn + 127) / 128;
    bmat2_kernel<<<nblk, 256, 0, stream>>>(X, E, Wfrag, bprime, T, t0, tn, TSEG, Bseg2);
    int nch = tn / 32;                            // 32-matrix L1 chains
    chain_kernel<<<nch / 4, 256, 0, stream>>>(
        Bseg2, nullptr, nch, 32, (long)TSEG, 1L,
        Sg + (size_t)(t0 / 32) * 1024, Eg + t0 / 32, nullptr);
  }

  int nch2 = NC1 / 64;  // 64 chains of 64 at L2
  chain_kernel<<<(nch2 + 3) / 4, 256, 0, stream>>>(
      (const uint4*)Sg, Eg, nch2, 64, 1L, 128L, Rf, ER, nullptr);
  chain_kernel<<<1, 64, 0, stream>>>(
      (const uint4*)Rf, ER, 1, 64, 1L, 128L, nullptr, Egrand, MT);

  finalize_kernel<<<1, 64, 0, stream>>>(il, E, Spart, NB0, MT, Egrand, out);
}